// Round 3
// baseline (58.369 us; speedup 1.0000x reference)
//
#include <hip/hip_runtime.h>
#include <math.h>

#define NB 81
#define NW 140
#define NL 36          // 9 rows + 9 cols + 9 diags + 9 anti-diags
#define PSZ (NL * 6)   // per-line: slot l*6 = 0 (exclusive base), l*6+1+pos = inclusive prefix
#define WINM 2097152.0f   // 2^21 win marker: prefix sums stay exact (<2^24)

struct Tables {
    unsigned long long lmlo[NL][5];  // window masks by (line,pos), cells 0..63 (pad = 0)
    unsigned long long lmhi[NL][5];  // cells 64..80
    unsigned char len[NL];           // windows in line (1..5)
    unsigned cellPS[NB][2];          // per cell: [0]=dir0 hi|lo<<8|dir1 hi<<16|lo<<24, [1]=dirs 2,3
};

constexpr Tables make_tables() {
    Tables t{};
    int minp[NB][4] = {}, maxp[NB][4] = {}, lofc[NB][4] = {};
    for (int a = 0; a < NB; ++a)
        for (int d = 0; d < 4; ++d) { minp[a][d] = 99; maxp[a][d] = -1; }
    const int DR[4] = {0, 1, 1, 1};
    const int DC[4] = {1, 0, 1, -1};
    for (int d = 0; d < 4; ++d)
        for (int r = 0; r < 9; ++r)
            for (int c = 0; c < 9; ++c) {
                const int er = r + 4 * DR[d], ec = c + 4 * DC[d];
                if (er < 0 || er > 8 || ec < 0 || ec > 8) continue;
                int l = 0;
                if (d == 0) l = r;
                else if (d == 1) l = 9 + c;
                else if (d == 2) l = 18 + (r - c + 4);       // diag id r-c in [-4,4]
                else l = 27 + (r + c - 4);                   // anti-diag r+c in [4,12]
                const int pos = t.len[l]++;
                unsigned long long lo = 0, hi = 0;
                for (int k = 0; k < 5; ++k) {
                    const int cell = (r + k * DR[d]) * 9 + (c + k * DC[d]);
                    if (cell < 64) lo |= 1ull << cell;
                    else           hi |= 1ull << (cell - 64);
                    lofc[cell][d] = l;
                    if (pos < minp[cell][d]) minp[cell][d] = pos;
                    if (pos > maxp[cell][d]) maxp[cell][d] = pos;
                }
                t.lmlo[l][pos] = lo; t.lmhi[l][pos] = hi;
            }
    for (int a = 0; a < NB; ++a) {
        unsigned q[2] = {0, 0};
        for (int d = 0; d < 4; ++d) {
            unsigned hiS = 0, loS = 0;   // empty range -> both point at P[0] == 0
            if (maxp[a][d] >= 0) {
                const int l = lofc[a][d];
                loS = (unsigned)(l * 6 + minp[a][d]);        // exclusive prefix slot
                hiS = (unsigned)(l * 6 + 1 + maxp[a][d]);    // inclusive prefix slot
            }
            q[d >> 1] |= (hiS | (loS << 8)) << (16 * (d & 1));
        }
        t.cellPS[a][0] = q[0]; t.cellPS[a][1] = q[1];
    }
    return t;
}

__device__ __constant__ Tables TAB = make_tables();
__device__ __constant__ float PT[6] = {0.f, 5.f, 50.f, 500.f, 5000.f, 100000.f};
__device__ __constant__ float DT[6] = {5.f, 45.f, 450.f, 4500.f, 95000.f, 0.f};

__device__ __forceinline__ float wave_sum(float v) {
#pragma unroll
    for (int m = 1; m < 64; m <<= 1) v += __shfl_xor(v, m, 64);
    return v;
}
__device__ __forceinline__ float wave_max(float v) {
#pragma unroll
    for (int m = 1; m < 64; m <<= 1) v = fmaxf(v, __shfl_xor(v, m, 64));
    return v;
}

__global__ __launch_bounds__(256) void heur9_kernel(const float* __restrict__ boards,
                                                    const int* __restrict__ cur,
                                                    float* __restrict__ out, int B) {
    __shared__ float sP[4][PSZ];
    const int wave = threadIdx.x >> 6;
    const int lane = threadIdx.x & 63;
    const int b = (blockIdx.x << 2) | wave;   // grid = B/4 exactly
    float* P = sP[wave];
    const float* brd = boards + b * NB;

    const float pf = (float)cur[b];
    const float of = 3.0f - pf;
    const float v1 = brd[lane];
    const float v2 = (lane < NB - 64) ? brd[lane + 64] : -1.0f;

    // Occupancy bitboards via wave ballot (wave-uniform).
    const unsigned long long p_lo = __ballot(v1 == pf);
    const unsigned long long p_hi = __ballot((lane < NB - 64) && v2 == pf);
    const unsigned long long o_lo = __ballot(v1 == of);
    const unsigned long long o_hi = __ballot((lane < NB - 64) && v2 == of);
    const unsigned long long e_lo = ~(p_lo | o_lo);
    const unsigned long long e_hi = ~(p_hi | o_hi);

    // Line pass: lane = line; compute window deltas + inclusive prefix in one sweep.
    float evp = 0.f;
    if (lane < NL) {
        const int len = TAB.len[lane];
        float run = 0.f;
        P[lane * 6] = 0.f;
#pragma unroll
        for (int pos = 0; pos < 5; ++pos) {
            const unsigned long long ml = TAB.lmlo[lane][pos];
            const unsigned long long mh = TAB.lmhi[lane][pos];
            const int pc = __popcll(p_lo & ml) + __popcll(p_hi & mh);
            const int oc = __popcll(o_lo & ml) + __popcll(o_hi & mh);
            float d = 0.f;
            if (oc == 0)      { d = DT[pc]; evp += PT[pc]; }  // PT[0]==0 covers pc>0 guard
            else if (pc == 0) { d = PT[oc]; evp -= PT[oc]; }
            if (pc == 4) d = WINM;            // only reachable via an empty member cell
            if (pos >= len) d = 0.f;          // pad windows (masks 0) contribute nothing
            run += d;
            P[lane * 6 + 1 + pos] = run;
        }
    }
    const float ev = wave_sum(evp);           // exact: integer multiples of 5 < 2^24
    __syncthreads();

    // Cell pass: 4 prefix differences per cell (one per direction).
    const unsigned a0 = TAB.cellPS[lane][0], a1 = TAB.cellPS[lane][1];
    float sd1 = (P[a0 & 255] - P[(a0 >> 8) & 255]) + (P[(a0 >> 16) & 255] - P[a0 >> 24])
              + (P[a1 & 255] - P[(a1 >> 8) & 255]) + (P[(a1 >> 16) & 255] - P[a1 >> 24]);
    float sd2 = 0.f;
    if (lane < NB - 64) {
        const unsigned b0 = TAB.cellPS[lane + 64][0], b1 = TAB.cellPS[lane + 64][1];
        sd2 = (P[b0 & 255] - P[(b0 >> 8) & 255]) + (P[(b0 >> 16) & 255] - P[b0 >> 24])
            + (P[b1 & 255] - P[(b1 >> 8) & 255]) + (P[(b1 >> 16) & 255] - P[b1 >> 24]);
    }
    const bool emp1 = (e_lo >> lane) & 1ull;
    const bool emp2 = (lane < NB - 64) && ((e_hi >> lane) & 1ull);
    float l1 = emp1 ? (sd1 >= 1.0e6f ? 100000.f : ev + sd1) : -1000000.f;
    float l2 = (lane < NB - 64)
                 ? (emp2 ? (sd2 >= 1.0e6f ? 100000.f : ev + sd2) : -1000000.f)
                 : -INFINITY;
    l1 *= 0.03f; l2 *= 0.03f;

    const float m = wave_max(fmaxf(l1, l2));
    const float e1 = __expf(l1 - m);
    const float e2 = (lane < NB - 64) ? __expf(l2 - m) : 0.f;
    const float inv = 1.0f / wave_sum(e1 + e2);

    out[b * NB + lane] = e1 * inv;
    if (lane < NB - 64) out[b * NB + lane + 64] = e2 * inv;
    if (lane == 0) {
        const float v = tanhf(ev * (1.f / 3000.f));
        out[B * NB + b] = fminf(fmaxf(v, -0.95f), 0.95f);
    }
}

extern "C" void kernel_launch(void* const* d_in, const int* in_sizes, int n_in,
                              void* d_out, int out_size, void* d_ws, size_t ws_size,
                              hipStream_t stream) {
    const float* boards = (const float*)d_in[0];
    const int* cur = (const int*)d_in[1];
    float* out = (float*)d_out;
    const int B = in_sizes[0] / NB;   // 2048
    heur9_kernel<<<B / 4, 256, 0, stream>>>(boards, cur, out, B);
}